// Round 13
// baseline (265.752 us; speedup 1.0000x reference)
//
#include <hip/hip_runtime.h>

#define FD 96
#define BSH 7       // 128 nodes per bucket
#define BNODES 128
#define NBLK 256    // blocks for 2D-histogram scatter

typedef float  f32x4 __attribute__((ext_vector_type(4)));
typedef short  s16x8 __attribute__((ext_vector_type(8)));

__device__ __forceinline__ unsigned short f2bf(float x) {
    unsigned u = __float_as_uint(x);
    u = (u + 0x7fffu + ((u >> 16) & 1u)) >> 16;
    return (unsigned short)u;
}
__device__ __forceinline__ float bflo(unsigned u) { return __uint_as_float(u << 16); }
__device__ __forceinline__ float bfhi(unsigned u) { return __uint_as_float(u & 0xffff0000u); }

__device__ __forceinline__ s16x8 pack8(const float t[8]) {
    union { unsigned u[4]; s16x8 v; } r;
    #pragma unroll
    for (int z = 0; z < 4; z++)
        r.u[z] = (unsigned)f2bf(t[2 * z]) | ((unsigned)f2bf(t[2 * z + 1]) << 16);
    return r.v;
}

// ---------------- bucketed CSR build (contention-free) ----------------

__global__ void k_h2d(const int* __restrict__ dst, int* __restrict__ hist2d,
                      int* __restrict__ bcnt, int E, int nbkt, int chunk) {
    __shared__ int hist[512];
    int tid = threadIdx.x, b = blockIdx.x;
    for (int i = tid; i < 512; i += 256) hist[i] = 0;
    __syncthreads();
    int lo = b * chunk, hi = min(lo + chunk, E);
    for (int i = lo + tid; i < hi; i += 256)
        atomicAdd(&hist[dst[i] >> BSH], 1);
    __syncthreads();
    for (int q = tid; q < nbkt; q += 256) {
        int hv = hist[q];
        hist2d[(size_t)q * NBLK + b] = hv;
        if (hv) atomicAdd(&bcnt[q], hv);
    }
}

__global__ void k_bscan(const int* __restrict__ bcnt, int* __restrict__ bbase, int nbkt) {
    __shared__ int sh[512];
    int tid = threadIdx.x;
    int v = (tid < nbkt) ? bcnt[tid] : 0;
    sh[tid] = v;
    __syncthreads();
    for (int off = 1; off < 512; off <<= 1) {
        int t = (tid >= off) ? sh[tid - off] : 0;
        __syncthreads();
        sh[tid] += t;
        __syncthreads();
    }
    int incl = sh[tid];
    if (tid < nbkt) bbase[tid] = incl - v;
    if (tid == nbkt - 1) bbase[nbkt] = incl;
}

__global__ void k_cscan(const int* __restrict__ hist2d, const int* __restrict__ bbase,
                        int* __restrict__ cursor2d) {
    __shared__ int sh[NBLK];
    int q = blockIdx.x, tid = threadIdx.x;
    int v = hist2d[(size_t)q * NBLK + tid];
    sh[tid] = v;
    __syncthreads();
    for (int off = 1; off < NBLK; off <<= 1) {
        int t = (tid >= off) ? sh[tid - off] : 0;
        __syncthreads();
        sh[tid] += t;
        __syncthreads();
    }
    cursor2d[(size_t)q * NBLK + tid] = bbase[q] + sh[tid] - v;
}

__global__ void k_scat(const int* __restrict__ src, const int* __restrict__ dst,
                       const int* __restrict__ cursor2d, uint2* __restrict__ ebuf,
                       int E, int nbkt, int chunk) {
    __shared__ int cur[512];
    int tid = threadIdx.x, b = blockIdx.x;
    for (int q = tid; q < nbkt; q += 256)
        cur[q] = cursor2d[(size_t)q * NBLK + b];
    __syncthreads();
    int lo = b * chunk, hi = min(lo + chunk, E);
    for (int i = lo + tid; i < hi; i += 256) {
        int d = dst[i];
        int p = atomicAdd(&cur[d >> BSH], 1);
        ebuf[p] = make_uint2((unsigned)d, (unsigned)src[i]);
    }
}

// per-bucket counting sort -> csr (orig src ids), perm-ordered rp2/re2/invd2, perm, inv_perm
__global__ void k_bsort(const uint2* __restrict__ ebuf, const int* __restrict__ bbase,
                        int* __restrict__ csr, int* __restrict__ rp2, int* __restrict__ re2,
                        float* __restrict__ invd2, int* __restrict__ perm,
                        int* __restrict__ inv_perm, int n) {
    __shared__ int cnt[BNODES];
    __shared__ int cur[BNODES];
    __shared__ int dh[64];
    const int b = blockIdx.x;
    const int tid = threadIdx.x;
    const int lo = bbase[b], hi = bbase[b + 1];
    if (tid < BNODES) cnt[tid] = 0;
    if (tid < 64) dh[tid] = 0;
    __syncthreads();
    for (int i = lo + tid; i < hi; i += blockDim.x)
        atomicAdd(&cnt[(int)ebuf[i].x - (b << BSH)], 1);
    __syncthreads();
    const int node = (b << BSH) + tid;
    const int v = (tid < BNODES) ? cnt[tid] : 0;
    const int dcl = min(v, 63);
    if (tid < BNODES && node < n) atomicAdd(&dh[dcl], 1);
    for (int off = 1; off < BNODES; off <<= 1) {
        int t = (tid < BNODES && tid >= off) ? cnt[tid - off] : 0;
        __syncthreads();
        if (tid < BNODES) cnt[tid] += t;
        __syncthreads();
    }
    int dv = (tid < 64) ? dh[tid] : 0;
    for (int off = 1; off < 64; off <<= 1) {
        int t = (tid < 64 && tid >= off) ? dh[tid - off] : 0;
        __syncthreads();
        if (tid < 64) dh[tid] += t;
        __syncthreads();
    }
    if (tid < 64) dh[tid] -= dv;
    __syncthreads();
    if (tid < BNODES) {
        int excl = cnt[tid] - v;
        if (node < n) {
            int rk = atomicAdd(&dh[dcl], 1);
            int slot = (b << BSH) + rk;
            perm[slot] = node;
            inv_perm[node] = slot;
            rp2[slot] = lo + excl;
            re2[slot] = lo + excl + v;
            invd2[slot] = (v > 0) ? (1.0f / (float)v) : 0.f;
        }
        cur[tid] = excl;
    }
    __syncthreads();
    for (int i = lo + tid; i < hi; i += blockDim.x) {
        uint2 e2 = ebuf[i];
        int local = (int)e2.x - (b << BSH);
        int p = lo + atomicAdd(&cur[local], 1);
        csr[p] = (int)e2.y;
    }
}

// translate csr original ids -> perm slots
__global__ void k_xlate(int* __restrict__ csr, const int* __restrict__ inv_perm, int E) {
    int i = blockIdx.x * blockDim.x + threadIdx.x;
    if (i < E) csr[i] = inv_perm[csr[i]];
}

// features fp32 (orig order) -> bf16 rows in perm order
__global__ void k_cvtp(const float* __restrict__ feat, const int* __restrict__ perm,
                       uint4* __restrict__ o, int n) {
    int g = blockIdx.x * blockDim.x + threadIdx.x;
    int i = g / 12;
    if (i >= n) return;
    int q = g - i * 12;
    int node = perm[i];
    const float4* row = (const float4*)(feat + (size_t)node * FD);
    float4 x = row[2 * q], y = row[2 * q + 1];
    uint4 r;
    r.x = (unsigned)f2bf(x.x) | ((unsigned)f2bf(x.y) << 16);
    r.y = (unsigned)f2bf(x.z) | ((unsigned)f2bf(x.w) << 16);
    r.z = (unsigned)f2bf(y.x) | ((unsigned)f2bf(y.y) << 16);
    r.w = (unsigned)f2bf(y.z) | ((unsigned)f2bf(y.w) << 16);
    o[g] = r;
}

// all three W (96x96 fp32 [k][f]) -> Wt bf16 [f][k], concatenated
__global__ void k_wprep3(const float* __restrict__ W1, const float* __restrict__ W2,
                         const float* __restrict__ W3, unsigned short* __restrict__ Wt) {
    int i = blockIdx.x * blockDim.x + threadIdx.x;
    if (i >= 3 * FD * FD) return;
    int m = i / (FD * FD), r = i - m * FD * FD;
    const float* W = (m == 0) ? W1 : ((m == 1) ? W2 : W3);
    int col = r % FD, k = r / FD;
    Wt[m * FD * FD + col * FD + k] = f2bf(W[r]);
}

// ---------------- aggregation: column-pass-blocked gather ----------------
// block = 256 threads = 64 rows x 4 chunk-threads. 3 soft-synchronized passes:
// pass p touches only chunks [4p,4p+4) of every row -> 3.2 MB working set (fits XCD L2).
// One 64B line per edge per pass. Norm (BN+ReLU of prev layer) applied per gathered value.

template<int NORM>
__global__ __launch_bounds__(256, 4) void k_agg(
    const uint4* __restrict__ h,
    const int* __restrict__ rp2, const int* __restrict__ re2,
    const float* __restrict__ invd2, const int* __restrict__ csr,
    const float* __restrict__ nA, const float* __restrict__ nC,
    uint4* __restrict__ t, int n)
{
    const int tid = threadIdx.x;
    const int rl = tid >> 2;        // 0..63 row within block
    const int qq = tid & 3;         // chunk-in-pass
    const int idx = blockIdx.x * 64 + rl;
    if (idx >= n) return;
    const int beg = rp2[idx];
    const int end = re2[idx];
    const float id = invd2[idx];

    #pragma unroll 1
    for (int p = 0; p < 3; p++) {
        const int q = p * 4 + qq;
        float a[8], c[8];
        if (NORM) {
            #pragma unroll
            for (int z = 0; z < 8; z++) { a[z] = nA[q * 8 + z]; c[z] = nC[q * 8 + z]; }
        }
        float acc8[8];
        #pragma unroll
        for (int z = 0; z < 8; z++) acc8[z] = 0.f;

        int e = beg;
        for (; e + 8 <= end; e += 8) {
            uint4 raw[8];
            #pragma unroll
            for (int u = 0; u < 8; u++) raw[u] = h[(size_t)csr[e + u] * 12 + q];
            #pragma unroll
            for (int u = 0; u < 8; u++) {
                float v[8];
                v[0] = bflo(raw[u].x); v[1] = bfhi(raw[u].x);
                v[2] = bflo(raw[u].y); v[3] = bfhi(raw[u].y);
                v[4] = bflo(raw[u].z); v[5] = bfhi(raw[u].z);
                v[6] = bflo(raw[u].w); v[7] = bfhi(raw[u].w);
                #pragma unroll
                for (int z = 0; z < 8; z++) {
                    float x = v[z];
                    if (NORM) x = fmaxf(fmaf(a[z], x, c[z]), 0.f);
                    acc8[z] += x;
                }
            }
        }
        for (; e < end; e++) {
            uint4 raw = h[(size_t)csr[e] * 12 + q];
            float v[8];
            v[0] = bflo(raw.x); v[1] = bfhi(raw.x);
            v[2] = bflo(raw.y); v[3] = bfhi(raw.y);
            v[4] = bflo(raw.z); v[5] = bfhi(raw.z);
            v[6] = bflo(raw.w); v[7] = bfhi(raw.w);
            #pragma unroll
            for (int z = 0; z < 8; z++) {
                float x = v[z];
                if (NORM) x = fmaxf(fmaf(a[z], x, c[z]), 0.f);
                acc8[z] += x;
            }
        }
        // self + mean combine
        uint4 rs = h[(size_t)idx * 12 + q];
        float xs[8];
        xs[0] = bflo(rs.x); xs[1] = bfhi(rs.x);
        xs[2] = bflo(rs.y); xs[3] = bfhi(rs.y);
        xs[4] = bflo(rs.z); xs[5] = bfhi(rs.z);
        xs[6] = bflo(rs.w); xs[7] = bfhi(rs.w);
        float o[8];
        #pragma unroll
        for (int z = 0; z < 8; z++) {
            float x = xs[z];
            if (NORM) x = fmaxf(fmaf(a[z], x, c[z]), 0.f);
            o[z] = fmaf(id, acc8[z], x);
        }
        uint4 pk;
        pk.x = (unsigned)f2bf(o[0]) | ((unsigned)f2bf(o[1]) << 16);
        pk.y = (unsigned)f2bf(o[2]) | ((unsigned)f2bf(o[3]) << 16);
        pk.z = (unsigned)f2bf(o[4]) | ((unsigned)f2bf(o[5]) << 16);
        pk.w = (unsigned)f2bf(o[6]) | ((unsigned)f2bf(o[7]) << 16);
        t[(size_t)idx * 12 + q] = pk;
    }
}

// ---------------- MFMA matmul: y = t @ W + b (rows are perm slots) ----------------

template<int STATS, int OBF>
__global__ void k_mm(const unsigned short* __restrict__ ta,
                     const unsigned short* __restrict__ Wt,
                     const float* __restrict__ bias, const int* __restrict__ perm,
                     unsigned short* __restrict__ yb, float* __restrict__ yf,
                     float* __restrict__ accg, int n)
{
    __shared__ float sred[2 * FD];
    const int tid  = threadIdx.x;
    const int lane = tid & 63;
    const int wv   = tid >> 6;
    const int colb = lane & 15;
    const int hg   = lane >> 4;
    const int rbase = blockIdx.x * 64 + wv * 16;
    const int r = rbase + colb;

    s16x8 a[3];
    if (r < n) {
        #pragma unroll
        for (int s = 0; s < 3; s++)
            a[s] = *reinterpret_cast<const s16x8*>(ta + (size_t)r * FD + s * 32 + hg * 8);
    } else {
        #pragma unroll
        for (int s = 0; s < 3; s++) a[s] = s16x8{0, 0, 0, 0, 0, 0, 0, 0};
    }
    s16x8 b[6][3];
    #pragma unroll
    for (int c2 = 0; c2 < 6; c2++)
        #pragma unroll
        for (int s = 0; s < 3; s++)
            b[c2][s] = *reinterpret_cast<const s16x8*>(Wt + (size_t)(c2 * 16 + colb) * FD + s * 32 + hg * 8);

    f32x4 acc[6];
    #pragma unroll
    for (int c2 = 0; c2 < 6; c2++) acc[c2] = (f32x4){0.f, 0.f, 0.f, 0.f};
    #pragma unroll
    for (int s = 0; s < 3; s++)
        #pragma unroll
        for (int c2 = 0; c2 < 6; c2++)
            acc[c2] = __builtin_amdgcn_mfma_f32_16x16x32_bf16(a[s], b[c2][s], acc[c2], 0, 0, 0);

    int orow[4];
    #pragma unroll
    for (int j = 0; j < 4; j++) {
        int rr = rbase + hg * 4 + j;
        orow[j] = (!OBF && rr < n) ? perm[rr] : rr;
    }
    float s1[6], s2[6];
    #pragma unroll
    for (int c2 = 0; c2 < 6; c2++) { s1[c2] = 0.f; s2[c2] = 0.f; }
    #pragma unroll
    for (int c2 = 0; c2 < 6; c2++) {
        float bc = bias[c2 * 16 + colb];
        #pragma unroll
        for (int j = 0; j < 4; j++) {
            int rr = rbase + hg * 4 + j;
            if (rr < n) {
                float y = acc[c2][j] + bc;
                if (OBF) yb[(size_t)rr * FD + c2 * 16 + colb] = f2bf(y);
                else     yf[(size_t)orow[j] * FD + c2 * 16 + colb] = y;
                if (STATS) { s1[c2] += y; s2[c2] = fmaf(y, y, s2[c2]); }
            }
        }
    }
    if (STATS) {
        if (tid < 2 * FD) sred[tid] = 0.f;
        __syncthreads();
        #pragma unroll
        for (int c2 = 0; c2 < 6; c2++) {
            float v1 = s1[c2], v2 = s2[c2];
            v1 += __shfl_xor(v1, 16, 64); v1 += __shfl_xor(v1, 32, 64);
            v2 += __shfl_xor(v2, 16, 64); v2 += __shfl_xor(v2, 32, 64);
            if (lane < 16) {
                atomicAdd(&sred[c2 * 16 + colb], v1);
                atomicAdd(&sred[FD + c2 * 16 + colb], v2);
            }
        }
        __syncthreads();
        if (tid < 2 * FD) atomicAdd(&accg[tid], sred[tid]);
    }
}

// BN constants: a = gamma*rsqrt(var+eps), c = beta - mu*a
__global__ void k_bnfin(const float* __restrict__ acc,
                        const float* __restrict__ gamma, const float* __restrict__ beta,
                        float* __restrict__ na, float* __restrict__ nc, float invN) {
    int f = threadIdx.x;
    float mu  = acc[f] * invN;
    float var = acc[FD + f] * invN - mu * mu;
    float a = gamma[f] * rsqrtf(var + 1e-5f);
    na[f] = a;
    nc[f] = beta[f] - mu * a;
}

extern "C" void kernel_launch(void* const* d_in, const int* in_sizes, int n_in,
                              void* d_out, int out_size, void* d_ws, size_t ws_size,
                              hipStream_t stream) {
    const float* feat = (const float*)d_in[0];
    const float* W1   = (const float*)d_in[1];
    const float* b1   = (const float*)d_in[2];
    const float* g1   = (const float*)d_in[3];
    const float* be1  = (const float*)d_in[4];
    const float* W2   = (const float*)d_in[5];
    const float* b2   = (const float*)d_in[6];
    const float* g2   = (const float*)d_in[7];
    const float* be2  = (const float*)d_in[8];
    const float* W3   = (const float*)d_in[9];
    const float* b3   = (const float*)d_in[10];
    const int*   src  = (const int*)d_in[11];
    const int*   dst  = (const int*)d_in[12];

    const int n = in_sizes[0] / FD;   // 50000
    const int e = in_sizes[11];       // 800000
    const int nbkt = (n + BNODES - 1) >> BSH;     // 391
    const int chunk = (e + NBLK - 1) / NBLK;      // 3125

    char* w = (char*)d_ws;
    unsigned short* hA  = (unsigned short*)w; w += (size_t)n * FD * 2;   // h (perm order)
    unsigned short* tb  = (unsigned short*)w; w += (size_t)n * FD * 2;   // t (ebuf alias)
    unsigned short* Wt  = (unsigned short*)w; w += (size_t)3 * FD * FD * 2;
    int*   csr     = (int*)w;   w += (size_t)e * 4;
    int*   bcnt    = (int*)w;   w += 512 * 4;          // zeroed
    float* acc1    = (float*)w; w += 2 * FD * 4;       // zeroed
    float* acc2    = (float*)w; w += 2 * FD * 4;       // zeroed
    int*   bbase   = (int*)w;   w += 513 * 4;
    int*   hist2d  = (int*)w;   w += (size_t)512 * NBLK * 4;
    int*   cursor2d= (int*)w;   w += (size_t)512 * NBLK * 4;
    int*   rp2     = (int*)w;   w += (size_t)n * 4;
    int*   re2     = (int*)w;   w += (size_t)n * 4;
    float* invd2   = (float*)w; w += (size_t)n * 4;
    int*   perm    = (int*)w;   w += (size_t)n * 4;
    int*   invp    = (int*)w;   w += (size_t)n * 4;
    float* na1     = (float*)w; w += FD * 4;
    float* nc1     = (float*)w; w += FD * 4;
    float* na2     = (float*)w; w += FD * 4;
    float* nc2     = (float*)w; w += FD * 4;

    uint2* ebuf = (uint2*)tb;   // dead after k_bsort, before layer-1 agg writes tb

    float* O = (float*)d_out;
    const float invN = 1.0f / (float)n;
    const int AGG_GRID = (n + 63) / 64;     // 782
    const int MM_GRID  = (n + 63) / 64;
    const int n12 = n * 12;

    hipMemsetAsync(bcnt, 0, (512 + 4 * FD) * 4, stream);
    k_h2d<<<NBLK, 256, 0, stream>>>(dst, hist2d, bcnt, e, nbkt, chunk);
    k_bscan<<<1, 512, 0, stream>>>(bcnt, bbase, nbkt);
    k_cscan<<<nbkt, NBLK, 0, stream>>>(hist2d, bbase, cursor2d);
    k_scat<<<NBLK, 256, 0, stream>>>(src, dst, cursor2d, ebuf, e, nbkt, chunk);
    k_bsort<<<nbkt, 256, 0, stream>>>(ebuf, bbase, csr, rp2, re2, invd2, perm, invp, n);
    k_xlate<<<(e + 255) / 256, 256, 0, stream>>>(csr, invp, e);
    k_cvtp<<<(n12 + 255) / 256, 256, 0, stream>>>(feat, perm, (uint4*)hA, n);
    k_wprep3<<<(3 * FD * FD + 255) / 256, 256, 0, stream>>>(W1, W2, W3, Wt);

    // layer 1: agg hA->tb, mm tb->hA (bf16 perm order), stats -> bn1
    k_agg<0><<<AGG_GRID, 256, 0, stream>>>((const uint4*)hA, rp2, re2, invd2, csr,
                                           nullptr, nullptr, (uint4*)tb, n);
    k_mm<1, 1><<<MM_GRID, 256, 0, stream>>>(tb, Wt, b1, perm, hA, nullptr, acc1, n);
    k_bnfin<<<1, FD, 0, stream>>>(acc1, g1, be1, na1, nc1, invN);

    // layer 2
    k_agg<1><<<AGG_GRID, 256, 0, stream>>>((const uint4*)hA, rp2, re2, invd2, csr,
                                           na1, nc1, (uint4*)tb, n);
    k_mm<1, 1><<<MM_GRID, 256, 0, stream>>>(tb, Wt + FD * FD, b2, perm, hA, nullptr, acc2, n);
    k_bnfin<<<1, FD, 0, stream>>>(acc2, g2, be2, na2, nc2, invN);

    // layer 3: mm writes fp32 to d_out in ORIGINAL row order via perm scatter
    k_agg<1><<<AGG_GRID, 256, 0, stream>>>((const uint4*)hA, rp2, re2, invd2, csr,
                                           na2, nc2, (uint4*)tb, n);
    k_mm<0, 0><<<MM_GRID, 256, 0, stream>>>(tb, Wt + 2 * FD * FD, b3, perm, nullptr, O, nullptr, n);
}

// Round 14
// 262.687 us; speedup vs baseline: 1.0117x; 1.0117x over previous
//
#include <hip/hip_runtime.h>

#define FD 96
#define BSH 7       // 128 nodes per bucket
#define BNODES 128
#define NBLK 256    // blocks for 2D-histogram scatter

typedef float  f32x4 __attribute__((ext_vector_type(4)));
typedef short  s16x8 __attribute__((ext_vector_type(8)));

__device__ __forceinline__ unsigned short f2bf(float x) {
    unsigned u = __float_as_uint(x);
    u = (u + 0x7fffu + ((u >> 16) & 1u)) >> 16;
    return (unsigned short)u;
}
__device__ __forceinline__ float bflo(unsigned u) { return __uint_as_float(u << 16); }
__device__ __forceinline__ float bfhi(unsigned u) { return __uint_as_float(u & 0xffff0000u); }

// ---------------- bucketed CSR build (contention-free, 6 kernels) ----------------

// per-(block,bucket) histogram, transposed; no global atomics
__global__ void k_h2d(const int* __restrict__ dst, int* __restrict__ hist2d,
                      int E, int nbkt, int chunk) {
    __shared__ int hist[512];
    int tid = threadIdx.x, b = blockIdx.x;
    for (int i = tid; i < 512; i += 256) hist[i] = 0;
    __syncthreads();
    int lo = b * chunk, hi = min(lo + chunk, E);
    for (int i = lo + tid; i < hi; i += 256)
        atomicAdd(&hist[dst[i] >> BSH], 1);
    __syncthreads();
    for (int q = tid; q < nbkt; q += 256)
        hist2d[(size_t)q * NBLK + b] = hist[q];
}

// per-bucket: scan own column -> local exclusive prefixes + bucket total; block 0 zeroes accs
__global__ void k_cscan(const int* __restrict__ hist2d, int* __restrict__ cursor2d,
                        int* __restrict__ bcnt, float* __restrict__ accz) {
    __shared__ int sh[NBLK];
    int q = blockIdx.x, tid = threadIdx.x;
    if (q == 0) for (int i = tid; i < 4 * FD; i += 256) accz[i] = 0.f;
    int v = hist2d[(size_t)q * NBLK + tid];
    sh[tid] = v;
    __syncthreads();
    for (int off = 1; off < NBLK; off <<= 1) {
        int t = (tid >= off) ? sh[tid - off] : 0;
        __syncthreads();
        sh[tid] += t;
        __syncthreads();
    }
    cursor2d[(size_t)q * NBLK + tid] = sh[tid] - v;   // local exclusive prefix
    if (tid == NBLK - 1) bcnt[q] = sh[tid];
}

// scan bucket totals (1 block)
__global__ void k_bscan(const int* __restrict__ bcnt, int* __restrict__ bbase, int nbkt) {
    __shared__ int sh[512];
    int tid = threadIdx.x;
    int v = (tid < nbkt) ? bcnt[tid] : 0;
    sh[tid] = v;
    __syncthreads();
    for (int off = 1; off < 512; off <<= 1) {
        int t = (tid >= off) ? sh[tid - off] : 0;
        __syncthreads();
        sh[tid] += t;
        __syncthreads();
    }
    int incl = sh[tid];
    if (tid < nbkt) bbase[tid] = incl - v;
    if (tid == nbkt - 1) bbase[nbkt] = incl;
}

// scatter into bucket-grouped ebuf using private per-(block,bucket) ranges
__global__ void k_scat(const int* __restrict__ src, const int* __restrict__ dst,
                       const int* __restrict__ cursor2d, const int* __restrict__ bbase,
                       uint2* __restrict__ ebuf, int E, int nbkt, int chunk) {
    __shared__ int cur[512];
    int tid = threadIdx.x, b = blockIdx.x;
    for (int q = tid; q < nbkt; q += 256)
        cur[q] = bbase[q] + cursor2d[(size_t)q * NBLK + b];
    __syncthreads();
    int lo = b * chunk, hi = min(lo + chunk, E);
    for (int i = lo + tid; i < hi; i += 256) {
        int d = dst[i];
        int p = atomicAdd(&cur[d >> BSH], 1);
        ebuf[p] = make_uint2((unsigned)d, (unsigned)src[i]);
    }
}

// per-bucket counting sort -> csr (orig src ids), perm-ordered rp2/re2/invd2, perm, inv_perm
__global__ void k_bsort(const uint2* __restrict__ ebuf, const int* __restrict__ bbase,
                        int* __restrict__ csr, int* __restrict__ rp2, int* __restrict__ re2,
                        float* __restrict__ invd2, int* __restrict__ perm,
                        int* __restrict__ inv_perm, int n) {
    __shared__ int cnt[BNODES];
    __shared__ int cur[BNODES];
    __shared__ int dh[64];
    const int b = blockIdx.x;
    const int tid = threadIdx.x;
    const int lo = bbase[b], hi = bbase[b + 1];
    if (tid < BNODES) cnt[tid] = 0;
    if (tid < 64) dh[tid] = 0;
    __syncthreads();
    for (int i = lo + tid; i < hi; i += blockDim.x)
        atomicAdd(&cnt[(int)ebuf[i].x - (b << BSH)], 1);
    __syncthreads();
    const int node = (b << BSH) + tid;
    const int v = (tid < BNODES) ? cnt[tid] : 0;
    const int dcl = min(v, 63);
    if (tid < BNODES && node < n) atomicAdd(&dh[dcl], 1);
    for (int off = 1; off < BNODES; off <<= 1) {
        int t = (tid < BNODES && tid >= off) ? cnt[tid - off] : 0;
        __syncthreads();
        if (tid < BNODES) cnt[tid] += t;
        __syncthreads();
    }
    int dv = (tid < 64) ? dh[tid] : 0;
    for (int off = 1; off < 64; off <<= 1) {
        int t = (tid < 64 && tid >= off) ? dh[tid - off] : 0;
        __syncthreads();
        if (tid < 64) dh[tid] += t;
        __syncthreads();
    }
    if (tid < 64) dh[tid] -= dv;
    __syncthreads();
    if (tid < BNODES) {
        int excl = cnt[tid] - v;
        if (node < n) {
            int rk = atomicAdd(&dh[dcl], 1);
            int slot = (b << BSH) + rk;
            perm[slot] = node;
            inv_perm[node] = slot;
            rp2[slot] = lo + excl;
            re2[slot] = lo + excl + v;
            invd2[slot] = (v > 0) ? (1.0f / (float)v) : 0.f;
        }
        cur[tid] = excl;
    }
    __syncthreads();
    for (int i = lo + tid; i < hi; i += blockDim.x) {
        uint2 e2 = ebuf[i];
        int local = (int)e2.x - (b << BSH);
        int p = lo + atomicAdd(&cur[local], 1);
        csr[p] = (int)e2.y;
    }
}

// fused prep: csr translate + feature cvt to perm order + W transpose/cvt
__global__ void k_prep(int* __restrict__ csr, const int* __restrict__ inv_perm, int E,
                       const float* __restrict__ feat, const int* __restrict__ perm,
                       uint4* __restrict__ hA, int n,
                       const float* __restrict__ W1, const float* __restrict__ W2,
                       const float* __restrict__ W3, unsigned short* __restrict__ Wt) {
    int i = blockIdx.x * blockDim.x + threadIdx.x;
    if (i < E) {
        csr[i] = inv_perm[csr[i]];
        return;
    }
    i -= E;
    const int n12 = n * 12;
    if (i < n12) {
        int row = i / 12, q = i - row * 12;
        int node = perm[row];
        const float4* rp = (const float4*)(feat + (size_t)node * FD);
        float4 x = rp[2 * q], y = rp[2 * q + 1];
        uint4 r;
        r.x = (unsigned)f2bf(x.x) | ((unsigned)f2bf(x.y) << 16);
        r.y = (unsigned)f2bf(x.z) | ((unsigned)f2bf(x.w) << 16);
        r.z = (unsigned)f2bf(y.x) | ((unsigned)f2bf(y.y) << 16);
        r.w = (unsigned)f2bf(y.z) | ((unsigned)f2bf(y.w) << 16);
        hA[i] = r;
        return;
    }
    i -= n12;
    if (i < 3 * FD * FD) {
        int m = i / (FD * FD), r = i - m * FD * FD;
        const float* W = (m == 0) ? W1 : ((m == 1) ? W2 : W3);
        int col = r % FD, k = r / FD;
        Wt[m * FD * FD + col * FD + k] = f2bf(W[r]);
    }
}

// ---------------- fused layer: column-pass gather + LDS t + MFMA + bias + stats ----------------
// block = 256 threads. Gather: 64 rows x 4 chunk-threads, 3 passes (R13 structure, proven).
// t lands in LDS (padded [64][13] uint4). mm tail: 4 waves x 16 rows, a-frags from LDS,
// 6 coltiles x 3 ksteps MFMA. BN constants of the PREVIOUS layer computed in-kernel from acc.

template<int NORM, int STATS, int OBF>
__global__ __launch_bounds__(256) void k_aggmm(
    const uint4* __restrict__ h,
    const int* __restrict__ rp2, const int* __restrict__ re2,
    const float* __restrict__ invd2, const int* __restrict__ csr,
    const float* __restrict__ accPrev, const float* __restrict__ gamma,
    const float* __restrict__ beta,
    const unsigned short* __restrict__ Wt, const float* __restrict__ bias,
    const int* __restrict__ perm,
    unsigned short* __restrict__ yb, float* __restrict__ yf,
    float* __restrict__ accg, int n, float invN)
{
    __shared__ uint4 t_lds[64][13];   // 13-pad -> spread banks
    __shared__ float sred[2 * FD];
    const int tid = threadIdx.x;
    const int rl = tid >> 2;        // row within block
    const int qq = tid & 3;         // chunk-in-pass
    const int idx = blockIdx.x * 64 + rl;
    const bool valid = (idx < n);
    int beg = 0, end = 0;
    float id = 0.f;
    if (valid) { beg = rp2[idx]; end = re2[idx]; id = invd2[idx]; }

    #pragma unroll 1
    for (int p = 0; p < 3; p++) {
        const int q = p * 4 + qq;
        float a[8], c[8];
        if (NORM) {
            #pragma unroll
            for (int z = 0; z < 8; z++) {
                int f = q * 8 + z;
                float mu  = accPrev[f] * invN;
                float var = accPrev[FD + f] * invN - mu * mu;
                float aa  = gamma[f] * rsqrtf(var + 1e-5f);
                a[z] = aa;
                c[z] = beta[f] - mu * aa;
            }
        }
        float o[8];
        #pragma unroll
        for (int z = 0; z < 8; z++) o[z] = 0.f;

        if (valid) {
            float acc8[8];
            #pragma unroll
            for (int z = 0; z < 8; z++) acc8[z] = 0.f;
            int e = beg;
            for (; e + 8 <= end; e += 8) {
                uint4 raw[8];
                #pragma unroll
                for (int u = 0; u < 8; u++) raw[u] = h[(size_t)csr[e + u] * 12 + q];
                #pragma unroll
                for (int u = 0; u < 8; u++) {
                    float v[8];
                    v[0] = bflo(raw[u].x); v[1] = bfhi(raw[u].x);
                    v[2] = bflo(raw[u].y); v[3] = bfhi(raw[u].y);
                    v[4] = bflo(raw[u].z); v[5] = bfhi(raw[u].z);
                    v[6] = bflo(raw[u].w); v[7] = bfhi(raw[u].w);
                    #pragma unroll
                    for (int z = 0; z < 8; z++) {
                        float x = v[z];
                        if (NORM) x = fmaxf(fmaf(a[z], x, c[z]), 0.f);
                        acc8[z] += x;
                    }
                }
            }
            for (; e < end; e++) {
                uint4 raw = h[(size_t)csr[e] * 12 + q];
                float v[8];
                v[0] = bflo(raw.x); v[1] = bfhi(raw.x);
                v[2] = bflo(raw.y); v[3] = bfhi(raw.y);
                v[4] = bflo(raw.z); v[5] = bfhi(raw.z);
                v[6] = bflo(raw.w); v[7] = bfhi(raw.w);
                #pragma unroll
                for (int z = 0; z < 8; z++) {
                    float x = v[z];
                    if (NORM) x = fmaxf(fmaf(a[z], x, c[z]), 0.f);
                    acc8[z] += x;
                }
            }
            uint4 rs = h[(size_t)idx * 12 + q];
            float xs[8];
            xs[0] = bflo(rs.x); xs[1] = bfhi(rs.x);
            xs[2] = bflo(rs.y); xs[3] = bfhi(rs.y);
            xs[4] = bflo(rs.z); xs[5] = bfhi(rs.z);
            xs[6] = bflo(rs.w); xs[7] = bfhi(rs.w);
            #pragma unroll
            for (int z = 0; z < 8; z++) {
                float x = xs[z];
                if (NORM) x = fmaxf(fmaf(a[z], x, c[z]), 0.f);
                o[z] = fmaf(id, acc8[z], x);
            }
        }
        uint4 pk;
        pk.x = (unsigned)f2bf(o[0]) | ((unsigned)f2bf(o[1]) << 16);
        pk.y = (unsigned)f2bf(o[2]) | ((unsigned)f2bf(o[3]) << 16);
        pk.z = (unsigned)f2bf(o[4]) | ((unsigned)f2bf(o[5]) << 16);
        pk.w = (unsigned)f2bf(o[6]) | ((unsigned)f2bf(o[7]) << 16);
        t_lds[rl][q] = pk;
    }
    __syncthreads();

    // ---- mm tail ----
    const int lane = tid & 63;
    const int wv   = tid >> 6;
    const int colb = lane & 15;
    const int hg   = lane >> 4;
    const int rbase = blockIdx.x * 64 + wv * 16;

    s16x8 a[3];
    #pragma unroll
    for (int s = 0; s < 3; s++)
        a[s] = *reinterpret_cast<const s16x8*>(&t_lds[wv * 16 + colb][s * 4 + hg]);

    s16x8 b[6][3];
    #pragma unroll
    for (int c2 = 0; c2 < 6; c2++)
        #pragma unroll
        for (int s = 0; s < 3; s++)
            b[c2][s] = *reinterpret_cast<const s16x8*>(Wt + (size_t)(c2 * 16 + colb) * FD + s * 32 + hg * 8);

    f32x4 acc[6];
    #pragma unroll
    for (int c2 = 0; c2 < 6; c2++) acc[c2] = (f32x4){0.f, 0.f, 0.f, 0.f};
    #pragma unroll
    for (int s = 0; s < 3; s++)
        #pragma unroll
        for (int c2 = 0; c2 < 6; c2++)
            acc[c2] = __builtin_amdgcn_mfma_f32_16x16x32_bf16(a[s], b[c2][s], acc[c2], 0, 0, 0);

    int orow[4];
    #pragma unroll
    for (int j = 0; j < 4; j++) {
        int rr = rbase + hg * 4 + j;
        orow[j] = (!OBF && rr < n) ? perm[rr] : rr;
    }
    float s1[6], s2[6];
    #pragma unroll
    for (int c2 = 0; c2 < 6; c2++) { s1[c2] = 0.f; s2[c2] = 0.f; }
    #pragma unroll
    for (int c2 = 0; c2 < 6; c2++) {
        float bc = bias[c2 * 16 + colb];
        #pragma unroll
        for (int j = 0; j < 4; j++) {
            int rr = rbase + hg * 4 + j;
            if (rr < n) {
                float y = acc[c2][j] + bc;
                if (OBF) yb[(size_t)rr * FD + c2 * 16 + colb] = f2bf(y);
                else     yf[(size_t)orow[j] * FD + c2 * 16 + colb] = y;
                if (STATS) { s1[c2] += y; s2[c2] = fmaf(y, y, s2[c2]); }
            }
        }
    }
    if (STATS) {
        if (tid < 2 * FD) sred[tid] = 0.f;
        __syncthreads();
        #pragma unroll
        for (int c2 = 0; c2 < 6; c2++) {
            float v1 = s1[c2], v2 = s2[c2];
            v1 += __shfl_xor(v1, 16, 64); v1 += __shfl_xor(v1, 32, 64);
            v2 += __shfl_xor(v2, 16, 64); v2 += __shfl_xor(v2, 32, 64);
            if (lane < 16) {
                atomicAdd(&sred[c2 * 16 + colb], v1);
                atomicAdd(&sred[FD + c2 * 16 + colb], v2);
            }
        }
        __syncthreads();
        if (tid < 2 * FD) atomicAdd(&accg[tid], sred[tid]);
    }
}

extern "C" void kernel_launch(void* const* d_in, const int* in_sizes, int n_in,
                              void* d_out, int out_size, void* d_ws, size_t ws_size,
                              hipStream_t stream) {
    const float* feat = (const float*)d_in[0];
    const float* W1   = (const float*)d_in[1];
    const float* b1   = (const float*)d_in[2];
    const float* g1   = (const float*)d_in[3];
    const float* be1  = (const float*)d_in[4];
    const float* W2   = (const float*)d_in[5];
    const float* b2   = (const float*)d_in[6];
    const float* g2   = (const float*)d_in[7];
    const float* be2  = (const float*)d_in[8];
    const float* W3   = (const float*)d_in[9];
    const float* b3   = (const float*)d_in[10];
    const int*   src  = (const int*)d_in[11];
    const int*   dst  = (const int*)d_in[12];

    const int n = in_sizes[0] / FD;   // 50000
    const int e = in_sizes[11];       // 800000
    const int nbkt = (n + BNODES - 1) >> BSH;     // 391
    const int chunk = (e + NBLK - 1) / NBLK;      // 3125

    char* w = (char*)d_ws;
    unsigned short* hA  = (unsigned short*)w; w += (size_t)n * FD * 2;   // perm-order h
    unsigned short* hB  = (unsigned short*)w; w += (size_t)n * FD * 2;   // ping-pong (ebuf alias)
    unsigned short* Wt  = (unsigned short*)w; w += (size_t)3 * FD * FD * 2;
    int*   csr     = (int*)w;   w += (size_t)e * 4;
    int*   bcnt    = (int*)w;   w += 512 * 4;
    float* acc1    = (float*)w; w += 2 * FD * 4;   // zeroed by k_cscan
    float* acc2    = (float*)w; w += 2 * FD * 4;
    int*   bbase   = (int*)w;   w += 513 * 4;
    int*   hist2d  = (int*)w;   w += (size_t)512 * NBLK * 4;
    int*   cursor2d= (int*)w;   w += (size_t)512 * NBLK * 4;
    int*   rp2     = (int*)w;   w += (size_t)n * 4;
    int*   re2     = (int*)w;   w += (size_t)n * 4;
    float* invd2   = (float*)w; w += (size_t)n * 4;
    int*   perm    = (int*)w;   w += (size_t)n * 4;
    int*   invp    = (int*)w;   w += (size_t)n * 4;

    uint2* ebuf = (uint2*)hB;   // dead after k_bsort, before layer 1 writes hB

    float* O = (float*)d_out;
    const float invN = 1.0f / (float)n;
    const int FUSE_GRID = (n + 63) / 64;     // 782
    const int n12 = n * 12;
    const int prep_items = e + n12 + 3 * FD * FD;

    k_h2d<<<NBLK, 256, 0, stream>>>(dst, hist2d, e, nbkt, chunk);
    k_cscan<<<nbkt, NBLK, 0, stream>>>(hist2d, cursor2d, bcnt, acc1);
    k_bscan<<<1, 512, 0, stream>>>(bcnt, bbase, nbkt);
    k_scat<<<NBLK, 256, 0, stream>>>(src, dst, cursor2d, bbase, ebuf, e, nbkt, chunk);
    k_bsort<<<nbkt, 256, 0, stream>>>(ebuf, bbase, csr, rp2, re2, invd2, perm, invp, n);
    k_prep<<<(prep_items + 255) / 256, 256, 0, stream>>>(csr, invp, e, feat, perm,
                                                         (uint4*)hA, n, W1, W2, W3, Wt);

    // layer 1: hA -> hB (bf16 perm order), stats -> acc1
    k_aggmm<0, 1, 1><<<FUSE_GRID, 256, 0, stream>>>(
        (const uint4*)hA, rp2, re2, invd2, csr, nullptr, nullptr, nullptr,
        Wt, b1, perm, hB, nullptr, acc1, n, invN);

    // layer 2: hB -> hA, norm from acc1/g1/be1, stats -> acc2
    k_aggmm<1, 1, 1><<<FUSE_GRID, 256, 0, stream>>>(
        (const uint4*)hB, rp2, re2, invd2, csr, acc1, g1, be1,
        Wt + FD * FD, b2, perm, hA, nullptr, acc2, n, invN);

    // layer 3: hA -> d_out fp32 (original order via perm), norm from acc2/g2/be2
    k_aggmm<1, 0, 0><<<FUSE_GRID, 256, 0, stream>>>(
        (const uint4*)hA, rp2, re2, invd2, csr, acc2, g2, be2,
        Wt + 2 * FD * FD, b3, perm, nullptr, O, nullptr, n, invN);
}

// Round 15
// 210.356 us; speedup vs baseline: 1.2633x; 1.2488x over previous
//
#include <hip/hip_runtime.h>

#define FD 96
#define BSH 7       // 128 nodes per bucket
#define BNODES 128
#define NBLK 256    // blocks for 2D-histogram scatter

typedef float  f32x4 __attribute__((ext_vector_type(4)));
typedef short  s16x8 __attribute__((ext_vector_type(8)));

__device__ __forceinline__ unsigned short f2bf(float x) {
    unsigned u = __float_as_uint(x);
    u = (u + 0x7fffu + ((u >> 16) & 1u)) >> 16;
    return (unsigned short)u;
}
__device__ __forceinline__ float bflo(unsigned u) { return __uint_as_float(u << 16); }
__device__ __forceinline__ float bfhi(unsigned u) { return __uint_as_float(u & 0xffff0000u); }

// ---------------- bucketed CSR build (contention-free, 6 kernels) ----------------

__global__ void k_h2d(const int* __restrict__ dst, int* __restrict__ hist2d,
                      int E, int nbkt, int chunk) {
    __shared__ int hist[512];
    int tid = threadIdx.x, b = blockIdx.x;
    for (int i = tid; i < 512; i += 256) hist[i] = 0;
    __syncthreads();
    int lo = b * chunk, hi = min(lo + chunk, E);
    for (int i = lo + tid; i < hi; i += 256)
        atomicAdd(&hist[dst[i] >> BSH], 1);
    __syncthreads();
    for (int q = tid; q < nbkt; q += 256)
        hist2d[(size_t)q * NBLK + b] = hist[q];
}

// per-bucket column scan; block 0 zeroes both BN acc arrays (4*FD floats)
__global__ void k_cscan(const int* __restrict__ hist2d, int* __restrict__ cursor2d,
                        int* __restrict__ bcnt, float* __restrict__ accz) {
    __shared__ int sh[NBLK];
    int q = blockIdx.x, tid = threadIdx.x;
    if (q == 0) for (int i = tid; i < 4 * FD; i += 256) accz[i] = 0.f;
    int v = hist2d[(size_t)q * NBLK + tid];
    sh[tid] = v;
    __syncthreads();
    for (int off = 1; off < NBLK; off <<= 1) {
        int t = (tid >= off) ? sh[tid - off] : 0;
        __syncthreads();
        sh[tid] += t;
        __syncthreads();
    }
    cursor2d[(size_t)q * NBLK + tid] = sh[tid] - v;
    if (tid == NBLK - 1) bcnt[q] = sh[tid];
}

__global__ void k_bscan(const int* __restrict__ bcnt, int* __restrict__ bbase, int nbkt) {
    __shared__ int sh[512];
    int tid = threadIdx.x;
    int v = (tid < nbkt) ? bcnt[tid] : 0;
    sh[tid] = v;
    __syncthreads();
    for (int off = 1; off < 512; off <<= 1) {
        int t = (tid >= off) ? sh[tid - off] : 0;
        __syncthreads();
        sh[tid] += t;
        __syncthreads();
    }
    int incl = sh[tid];
    if (tid < nbkt) bbase[tid] = incl - v;
    if (tid == nbkt - 1) bbase[nbkt] = incl;
}

__global__ void k_scat(const int* __restrict__ src, const int* __restrict__ dst,
                       const int* __restrict__ cursor2d, const int* __restrict__ bbase,
                       uint2* __restrict__ ebuf, int E, int nbkt, int chunk) {
    __shared__ int cur[512];
    int tid = threadIdx.x, b = blockIdx.x;
    for (int q = tid; q < nbkt; q += 256)
        cur[q] = bbase[q] + cursor2d[(size_t)q * NBLK + b];
    __syncthreads();
    int lo = b * chunk, hi = min(lo + chunk, E);
    for (int i = lo + tid; i < hi; i += 256) {
        int d = dst[i];
        int p = atomicAdd(&cur[d >> BSH], 1);
        ebuf[p] = make_uint2((unsigned)d, (unsigned)src[i]);
    }
}

__global__ void k_bsort(const uint2* __restrict__ ebuf, const int* __restrict__ bbase,
                        int* __restrict__ csr, int* __restrict__ rp2, int* __restrict__ re2,
                        float* __restrict__ invd2, int* __restrict__ perm,
                        int* __restrict__ inv_perm, int n) {
    __shared__ int cnt[BNODES];
    __shared__ int cur[BNODES];
    __shared__ int dh[64];
    const int b = blockIdx.x;
    const int tid = threadIdx.x;
    const int lo = bbase[b], hi = bbase[b + 1];
    if (tid < BNODES) cnt[tid] = 0;
    if (tid < 64) dh[tid] = 0;
    __syncthreads();
    for (int i = lo + tid; i < hi; i += blockDim.x)
        atomicAdd(&cnt[(int)ebuf[i].x - (b << BSH)], 1);
    __syncthreads();
    const int node = (b << BSH) + tid;
    const int v = (tid < BNODES) ? cnt[tid] : 0;
    const int dcl = min(v, 63);
    if (tid < BNODES && node < n) atomicAdd(&dh[dcl], 1);
    for (int off = 1; off < BNODES; off <<= 1) {
        int t = (tid < BNODES && tid >= off) ? cnt[tid - off] : 0;
        __syncthreads();
        if (tid < BNODES) cnt[tid] += t;
        __syncthreads();
    }
    int dv = (tid < 64) ? dh[tid] : 0;
    for (int off = 1; off < 64; off <<= 1) {
        int t = (tid < 64 && tid >= off) ? dh[tid - off] : 0;
        __syncthreads();
        if (tid < 64) dh[tid] += t;
        __syncthreads();
    }
    if (tid < 64) dh[tid] -= dv;
    __syncthreads();
    if (tid < BNODES) {
        int excl = cnt[tid] - v;
        if (node < n) {
            int rk = atomicAdd(&dh[dcl], 1);
            int slot = (b << BSH) + rk;
            perm[slot] = node;
            inv_perm[node] = slot;
            rp2[slot] = lo + excl;
            re2[slot] = lo + excl + v;
            invd2[slot] = (v > 0) ? (1.0f / (float)v) : 0.f;
        }
        cur[tid] = excl;
    }
    __syncthreads();
    for (int i = lo + tid; i < hi; i += blockDim.x) {
        uint2 e2 = ebuf[i];
        int local = (int)e2.x - (b << BSH);
        int p = lo + atomicAdd(&cur[local], 1);
        csr[p] = (int)e2.y;
    }
}

// fused prep: csr translate + feature cvt to perm order + W transpose/cvt
__global__ void k_prep(int* __restrict__ csr, const int* __restrict__ inv_perm, int E,
                       const float* __restrict__ feat, const int* __restrict__ perm,
                       uint4* __restrict__ hA, int n,
                       const float* __restrict__ W1, const float* __restrict__ W2,
                       const float* __restrict__ W3, unsigned short* __restrict__ Wt) {
    int i = blockIdx.x * blockDim.x + threadIdx.x;
    if (i < E) {
        csr[i] = inv_perm[csr[i]];
        return;
    }
    i -= E;
    const int n12 = n * 12;
    if (i < n12) {
        int row = i / 12, q = i - row * 12;
        int node = perm[row];
        const float4* rp = (const float4*)(feat + (size_t)node * FD);
        float4 x = rp[2 * q], y = rp[2 * q + 1];
        uint4 r;
        r.x = (unsigned)f2bf(x.x) | ((unsigned)f2bf(x.y) << 16);
        r.y = (unsigned)f2bf(x.z) | ((unsigned)f2bf(x.w) << 16);
        r.z = (unsigned)f2bf(y.x) | ((unsigned)f2bf(y.y) << 16);
        r.w = (unsigned)f2bf(y.z) | ((unsigned)f2bf(y.w) << 16);
        hA[i] = r;
        return;
    }
    i -= n12;
    if (i < 3 * FD * FD) {
        int m = i / (FD * FD), r = i - m * FD * FD;
        const float* W = (m == 0) ? W1 : ((m == 1) ? W2 : W3);
        int col = r % FD, k = r / FD;
        Wt[m * FD * FD + col * FD + k] = f2bf(W[r]);
    }
}

// ---------------- aggregation: 12 threads/row (max TLP), BN of prev layer folded ----------------
// rows perm-ordered (degree-sorted) -> no indirection, low wave divergence.

template<int NORM>
__global__ __launch_bounds__(256, 4) void k_agg(
    const uint4* __restrict__ h,
    const int* __restrict__ rp2, const int* __restrict__ re2,
    const float* __restrict__ invd2, const int* __restrict__ csr,
    const float* __restrict__ accPrev, const float* __restrict__ gamma,
    const float* __restrict__ beta, float invN,
    uint4* __restrict__ t, int n)
{
    int g = blockIdx.x * blockDim.x + threadIdx.x;
    int row = g / 12;
    if (row >= n) return;
    int q = g - row * 12;
    float a[8], c[8];
    if (NORM) {
        #pragma unroll
        for (int z = 0; z < 8; z++) {
            int f = q * 8 + z;
            float mu  = accPrev[f] * invN;
            float var = accPrev[FD + f] * invN - mu * mu;
            float aa  = gamma[f] * rsqrtf(var + 1e-5f);
            a[z] = aa;
            c[z] = beta[f] - mu * aa;
        }
    }
    float acc8[8];
    #pragma unroll
    for (int z = 0; z < 8; z++) acc8[z] = 0.f;

    int e = rp2[row];
    const int end = re2[row];
    for (; e + 8 <= end; e += 8) {
        uint4 raw[8];
        #pragma unroll
        for (int u = 0; u < 8; u++) raw[u] = h[(size_t)csr[e + u] * 12 + q];
        #pragma unroll
        for (int u = 0; u < 8; u++) {
            float v[8];
            v[0] = bflo(raw[u].x); v[1] = bfhi(raw[u].x);
            v[2] = bflo(raw[u].y); v[3] = bfhi(raw[u].y);
            v[4] = bflo(raw[u].z); v[5] = bfhi(raw[u].z);
            v[6] = bflo(raw[u].w); v[7] = bfhi(raw[u].w);
            #pragma unroll
            for (int z = 0; z < 8; z++) {
                float x = v[z];
                if (NORM) x = fmaxf(fmaf(a[z], x, c[z]), 0.f);
                acc8[z] += x;
            }
        }
    }
    for (; e < end; e++) {
        uint4 raw = h[(size_t)csr[e] * 12 + q];
        float v[8];
        v[0] = bflo(raw.x); v[1] = bfhi(raw.x);
        v[2] = bflo(raw.y); v[3] = bfhi(raw.y);
        v[4] = bflo(raw.z); v[5] = bfhi(raw.z);
        v[6] = bflo(raw.w); v[7] = bfhi(raw.w);
        #pragma unroll
        for (int z = 0; z < 8; z++) {
            float x = v[z];
            if (NORM) x = fmaxf(fmaf(a[z], x, c[z]), 0.f);
            acc8[z] += x;
        }
    }
    uint4 rs = h[(size_t)row * 12 + q];
    float xs[8];
    xs[0] = bflo(rs.x); xs[1] = bfhi(rs.x);
    xs[2] = bflo(rs.y); xs[3] = bfhi(rs.y);
    xs[4] = bflo(rs.z); xs[5] = bfhi(rs.z);
    xs[6] = bflo(rs.w); xs[7] = bfhi(rs.w);
    float id = invd2[row];
    float o[8];
    #pragma unroll
    for (int z = 0; z < 8; z++) {
        float x = xs[z];
        if (NORM) x = fmaxf(fmaf(a[z], x, c[z]), 0.f);
        o[z] = fmaf(id, acc8[z], x);
    }
    uint4 pk;
    pk.x = (unsigned)f2bf(o[0]) | ((unsigned)f2bf(o[1]) << 16);
    pk.y = (unsigned)f2bf(o[2]) | ((unsigned)f2bf(o[3]) << 16);
    pk.z = (unsigned)f2bf(o[4]) | ((unsigned)f2bf(o[5]) << 16);
    pk.w = (unsigned)f2bf(o[6]) | ((unsigned)f2bf(o[7]) << 16);
    t[(size_t)row * 12 + q] = pk;
}

// ---------------- MFMA matmul: y = t @ W + b (rows are perm slots) ----------------

template<int STATS, int OBF>
__global__ void k_mm(const unsigned short* __restrict__ ta,
                     const unsigned short* __restrict__ Wt,
                     const float* __restrict__ bias, const int* __restrict__ perm,
                     unsigned short* __restrict__ yb, float* __restrict__ yf,
                     float* __restrict__ accg, int n)
{
    __shared__ float sred[2 * FD];
    const int tid  = threadIdx.x;
    const int lane = tid & 63;
    const int wv   = tid >> 6;
    const int colb = lane & 15;
    const int hg   = lane >> 4;
    const int rbase = blockIdx.x * 64 + wv * 16;
    const int r = rbase + colb;

    s16x8 a[3];
    if (r < n) {
        #pragma unroll
        for (int s = 0; s < 3; s++)
            a[s] = *reinterpret_cast<const s16x8*>(ta + (size_t)r * FD + s * 32 + hg * 8);
    } else {
        #pragma unroll
        for (int s = 0; s < 3; s++) a[s] = s16x8{0, 0, 0, 0, 0, 0, 0, 0};
    }
    s16x8 b[6][3];
    #pragma unroll
    for (int c2 = 0; c2 < 6; c2++)
        #pragma unroll
        for (int s = 0; s < 3; s++)
            b[c2][s] = *reinterpret_cast<const s16x8*>(Wt + (size_t)(c2 * 16 + colb) * FD + s * 32 + hg * 8);

    f32x4 acc[6];
    #pragma unroll
    for (int c2 = 0; c2 < 6; c2++) acc[c2] = (f32x4){0.f, 0.f, 0.f, 0.f};
    #pragma unroll
    for (int s = 0; s < 3; s++)
        #pragma unroll
        for (int c2 = 0; c2 < 6; c2++)
            acc[c2] = __builtin_amdgcn_mfma_f32_16x16x32_bf16(a[s], b[c2][s], acc[c2], 0, 0, 0);

    int orow[4];
    #pragma unroll
    for (int j = 0; j < 4; j++) {
        int rr = rbase + hg * 4 + j;
        orow[j] = (!OBF && rr < n) ? perm[rr] : rr;
    }
    float s1[6], s2[6];
    #pragma unroll
    for (int c2 = 0; c2 < 6; c2++) { s1[c2] = 0.f; s2[c2] = 0.f; }
    #pragma unroll
    for (int c2 = 0; c2 < 6; c2++) {
        float bc = bias[c2 * 16 + colb];
        #pragma unroll
        for (int j = 0; j < 4; j++) {
            int rr = rbase + hg * 4 + j;
            if (rr < n) {
                float y = acc[c2][j] + bc;
                if (OBF) yb[(size_t)rr * FD + c2 * 16 + colb] = f2bf(y);
                else     yf[(size_t)orow[j] * FD + c2 * 16 + colb] = y;
                if (STATS) { s1[c2] += y; s2[c2] = fmaf(y, y, s2[c2]); }
            }
        }
    }
    if (STATS) {
        if (tid < 2 * FD) sred[tid] = 0.f;
        __syncthreads();
        #pragma unroll
        for (int c2 = 0; c2 < 6; c2++) {
            float v1 = s1[c2], v2 = s2[c2];
            v1 += __shfl_xor(v1, 16, 64); v1 += __shfl_xor(v1, 32, 64);
            v2 += __shfl_xor(v2, 16, 64); v2 += __shfl_xor(v2, 32, 64);
            if (lane < 16) {
                atomicAdd(&sred[c2 * 16 + colb], v1);
                atomicAdd(&sred[FD + c2 * 16 + colb], v2);
            }
        }
        __syncthreads();
        if (tid < 2 * FD) atomicAdd(&accg[tid], sred[tid]);
    }
}

extern "C" void kernel_launch(void* const* d_in, const int* in_sizes, int n_in,
                              void* d_out, int out_size, void* d_ws, size_t ws_size,
                              hipStream_t stream) {
    const float* feat = (const float*)d_in[0];
    const float* W1   = (const float*)d_in[1];
    const float* b1   = (const float*)d_in[2];
    const float* g1   = (const float*)d_in[3];
    const float* be1  = (const float*)d_in[4];
    const float* W2   = (const float*)d_in[5];
    const float* b2   = (const float*)d_in[6];
    const float* g2   = (const float*)d_in[7];
    const float* be2  = (const float*)d_in[8];
    const float* W3   = (const float*)d_in[9];
    const float* b3   = (const float*)d_in[10];
    const int*   src  = (const int*)d_in[11];
    const int*   dst  = (const int*)d_in[12];

    const int n = in_sizes[0] / FD;   // 50000
    const int e = in_sizes[11];       // 800000
    const int nbkt = (n + BNODES - 1) >> BSH;     // 391
    const int chunk = (e + NBLK - 1) / NBLK;      // 3125

    char* w = (char*)d_ws;
    unsigned short* hA  = (unsigned short*)w; w += (size_t)n * FD * 2;   // perm-order h
    unsigned short* tb  = (unsigned short*)w; w += (size_t)n * FD * 2;   // t buffer (ebuf alias)
    unsigned short* Wt  = (unsigned short*)w; w += (size_t)3 * FD * FD * 2;
    int*   csr     = (int*)w;   w += (size_t)e * 4;
    int*   bcnt    = (int*)w;   w += 512 * 4;
    float* acc1    = (float*)w; w += 2 * FD * 4;   // zeroed by k_cscan (with acc2)
    float* acc2    = (float*)w; w += 2 * FD * 4;
    int*   bbase   = (int*)w;   w += 513 * 4;
    int*   hist2d  = (int*)w;   w += (size_t)512 * NBLK * 4;
    int*   cursor2d= (int*)w;   w += (size_t)512 * NBLK * 4;
    int*   rp2     = (int*)w;   w += (size_t)n * 4;
    int*   re2     = (int*)w;   w += (size_t)n * 4;
    float* invd2   = (float*)w; w += (size_t)n * 4;
    int*   perm    = (int*)w;   w += (size_t)n * 4;
    int*   invp    = (int*)w;   w += (size_t)n * 4;

    uint2* ebuf = (uint2*)tb;                      // dead after k_bsort
    unsigned short* hB = (unsigned short*)d_out;   // bf16 ping-pong inside d_out
    float* O = (float*)d_out;
    const float invN = 1.0f / (float)n;
    const int AGG_GRID = (n * 12 + 255) / 256;     // 2344
    const int MM_GRID  = (n + 63) / 64;            // 782
    const int n12 = n * 12;
    const int prep_items = e + n12 + 3 * FD * FD;

    k_h2d<<<NBLK, 256, 0, stream>>>(dst, hist2d, e, nbkt, chunk);
    k_cscan<<<nbkt, NBLK, 0, stream>>>(hist2d, cursor2d, bcnt, acc1);
    k_bscan<<<1, 512, 0, stream>>>(bcnt, bbase, nbkt);
    k_scat<<<NBLK, 256, 0, stream>>>(src, dst, cursor2d, bbase, ebuf, e, nbkt, chunk);
    k_bsort<<<nbkt, 256, 0, stream>>>(ebuf, bbase, csr, rp2, re2, invd2, perm, invp, n);
    k_prep<<<(prep_items + 255) / 256, 256, 0, stream>>>(csr, invp, e, feat, perm,
                                                         (uint4*)hA, n, W1, W2, W3, Wt);

    // layer 1: agg hA->tb, mm tb->hB (bf16 in d_out), stats->acc1
    k_agg<0><<<AGG_GRID, 256, 0, stream>>>((const uint4*)hA, rp2, re2, invd2, csr,
                                           nullptr, nullptr, nullptr, invN, (uint4*)tb, n);
    k_mm<1, 1><<<MM_GRID, 256, 0, stream>>>(tb, Wt, b1, perm, hB, nullptr, acc1, n);

    // layer 2: agg hB->tb (BN from acc1), mm tb->hA, stats->acc2
    k_agg<1><<<AGG_GRID, 256, 0, stream>>>((const uint4*)hB, rp2, re2, invd2, csr,
                                           acc1, g1, be1, invN, (uint4*)tb, n);
    k_mm<1, 1><<<MM_GRID, 256, 0, stream>>>(tb, Wt + FD * FD, b2, perm, hA, nullptr, acc2, n);

    // layer 3: agg hA->tb (BN from acc2), mm tb->d_out fp32 (original order via perm)
    k_agg<1><<<AGG_GRID, 256, 0, stream>>>((const uint4*)hA, rp2, re2, invd2, csr,
                                           acc2, g2, be2, invN, (uint4*)tb, n);
    k_mm<0, 0><<<MM_GRID, 256, 0, stream>>>(tb, Wt + 2 * FD * FD, b3, perm, nullptr, O, nullptr, n);
}